// Round 19
// baseline (1699.678 us; speedup 1.0000x reference)
//
#include <hip/hip_runtime.h>

#define NATOMS 400000
#define NEDGES 800000
#define NMOLS  13000
#define AF 133
#define BFdim 14
#define BFD 147

typedef __attribute__((ext_vector_type(8))) short  s16x8;
typedef __attribute__((ext_vector_type(8))) __bf16 b16x8;
typedef __attribute__((ext_vector_type(4))) float  f32x4;

__device__ __forceinline__ float bf2f(unsigned short u){
  union { unsigned int i; float f; } v; v.i = ((unsigned int)u) << 16; return v.f;
}
__device__ __forceinline__ unsigned short f2bf(float f){
  union { float ff; unsigned int i; } v; v.ff = f;
  unsigned int b = v.i + 0x7fffu + ((v.i >> 16) & 1u);
  return (unsigned short)(b >> 16);
}
__device__ __forceinline__ unsigned int pk2(float a, float b){
  unsigned int r;
  asm("v_cvt_pk_bf16_f32 %0, %1, %2" : "=v"(r) : "v"(a), "v"(b));
  return r;
}
__device__ __forceinline__ f32x4 mfma16(s16x8 a, s16x8 b, f32x4 c){
  return __builtin_amdgcn_mfma_f32_16x16x32_bf16(
      __builtin_bit_cast(b16x8, a), __builtin_bit_cast(b16x8, b), c, 0, 0, 0);
}
__device__ __forceinline__ void gload_lds16(const void* g, void* lds){
  __builtin_amdgcn_global_load_lds(
      (const __attribute__((address_space(1))) void*)g,
      (__attribute__((address_space(3))) void*)lds, 16, 0, 0);
}
__device__ __forceinline__ uint4 relu8(uint4 v){
  ushort* pv = (ushort*)&v;
  #pragma unroll
  for (int j = 0; j < 8; j++) pv[j] = (pv[j] & 0x8000u) ? 0 : pv[j];
  return v;
}

// ---------------- weight prep: fp32 -> bf16 fragment order ----------------
__global__ void k_prep_weights(const float* __restrict__ W_i, const float* __restrict__ W_h,
                               const float* __restrict__ W_o, const float* __restrict__ node_W,
                               const float* __restrict__ edge_W,
                               ushort* __restrict__ Wif, ushort* __restrict__ Wof1,
                               ushort* __restrict__ Whf, ushort* __restrict__ Wof2,
                               ushort* __restrict__ nWf, ushort* __restrict__ eWf){
  int gid = blockIdx.x * 256 + threadIdx.x;
  ushort* dst; const float* src; int KB, Kv, Ns, idx;
  if      (gid <  40960){ idx = gid;          dst = Wif;  src = W_i;          KB = 5; Kv = 147; Ns = 256; }
  else if (gid <  81920){ idx = gid -  40960; dst = Wof1; src = W_o;          KB = 5; Kv = 133; Ns = 256; }
  else if (gid < 147456){ idx = gid -  81920; dst = Whf;  src = W_h;          KB = 8; Kv = 256; Ns = 256; }
  else if (gid < 212992){ idx = gid - 147456; dst = Wof2; src = W_o + 133*256;KB = 8; Kv = 256; Ns = 256; }
  else if (gid < 249856){ idx = gid - 212992; dst = nWf;  src = node_W;       KB = 8; Kv = 256; Ns = 133; }
  else if (gid < 253952){ idx = gid - 249856; dst = eWf;  src = edge_W;       KB = 8; Kv = 256; Ns = 14;  }
  else return;
  int j = idx & 7, lane = (idx >> 3) & 63, fi = idx >> 9;
  int kb = fi % KB, nb = fi / KB;
  int k = kb * 32 + ((lane >> 4) << 3) + j;
  int n = nb * 16 + (lane & 15);
  float v = 0.f;
  if (k < Kv && n < Ns) v = src[(size_t)k * Ns + n];
  dst[idx] = f2bf(v);
}

// ---------------- CSR build over src ----------------
__global__ void k_hist(const int* __restrict__ key, int* __restrict__ deg){
  int e = blockIdx.x * 256 + threadIdx.x;
  if (e < NEDGES) atomicAdd(&deg[key[e]], 1);
}
__global__ void k_blocksum(const int* __restrict__ deg, int* __restrict__ bsum){
  __shared__ int s[256];
  int i = blockIdx.x * 256 + threadIdx.x;
  s[threadIdx.x] = (i < NATOMS) ? deg[i] : 0;
  __syncthreads();
  for (int st = 128; st > 0; st >>= 1){
    if (threadIdx.x < st) s[threadIdx.x] += s[threadIdx.x + st];
    __syncthreads();
  }
  if (threadIdx.x == 0) bsum[blockIdx.x] = s[0];
}
#define NBLK 1563
__global__ void k_scanblk(const int* __restrict__ bs, int* __restrict__ bo){
  __shared__ int s[2048];
  int t = threadIdx.x;
  s[2*t]   = (2*t   < NBLK) ? bs[2*t]   : 0;
  s[2*t+1] = (2*t+1 < NBLK) ? bs[2*t+1] : 0;
  int offset = 1;
  for (int d = 1024; d > 0; d >>= 1){
    __syncthreads();
    if (t < d){ int ai = offset*(2*t+1)-1, bi = offset*(2*t+2)-1; s[bi] += s[ai]; }
    offset <<= 1;
  }
  __syncthreads();
  if (t == 0) s[2047] = 0;
  for (int d = 1; d < 2048; d <<= 1){
    offset >>= 1;
    __syncthreads();
    if (t < d){ int ai = offset*(2*t+1)-1, bi = offset*(2*t+2)-1;
                int tmp = s[ai]; s[ai] = s[bi]; s[bi] += tmp; }
  }
  __syncthreads();
  if (2*t   < NBLK) bo[2*t]   = s[2*t];
  if (2*t+1 < NBLK) bo[2*t+1] = s[2*t+1];
}
__global__ void k_offs(const int* __restrict__ deg, const int* __restrict__ bo,
                       int* __restrict__ offs, int* __restrict__ cursor){
  __shared__ int s1[256], s2[256];
  int t = threadIdx.x;
  int i = blockIdx.x * 256 + t;
  int v = (i < NATOMS) ? deg[i] : 0;
  s1[t] = v;
  __syncthreads();
  int* rd = s1; int* wr = s2;
  for (int ofs = 1; ofs < 256; ofs <<= 1){
    wr[t] = rd[t] + ((t >= ofs) ? rd[t - ofs] : 0);
    __syncthreads();
    int* tmp = rd; rd = wr; wr = tmp;
  }
  if (i < NATOMS){
    int excl = rd[t] - v + bo[blockIdx.x];
    offs[i] = excl; cursor[i] = excl;
  }
  if (i == 0) offs[NATOMS] = NEDGES;
}
__global__ void k_fill(const int* __restrict__ key, int* __restrict__ cursor,
                       int* __restrict__ elist, int* __restrict__ pos){
  int e = blockIdx.x * 256 + threadIdx.x;
  if (e < NEDGES){ int p = atomicAdd(&cursor[key[e]], 1); elist[p] = e; pos[e] = p; }
}
__global__ void k_maps(const int* __restrict__ elist, const int* __restrict__ pos,
                       int* __restrict__ revp){
  int i = blockIdx.x * 256 + threadIdx.x;
  if (i < NEDGES) revp[i] = pos[elist[i] ^ 1];
}
__global__ void k_molstart(const int* __restrict__ atom_mol, int* __restrict__ molst){
  int m = blockIdx.x * 256 + threadIdx.x;
  if (m > NMOLS) return;
  int lo = 0, hi = NATOMS;
  while (lo < hi){ int mid = (lo + hi) >> 1; if (atom_mol[mid] < m) lo = mid + 1; else hi = mid; }
  molst[m] = lo;
}

// ---------------- fused (512 thr): stage fp32 f_bonds ; inp/Y0 GEMMs ; wide scatters ----------------
__global__ __launch_bounds__(512) void k_fused_inpY(
    const float* __restrict__ FB, const ushort* __restrict__ Wif,
    const ushort* __restrict__ Whf, const int* __restrict__ pos,
    ushort* __restrict__ inp, ushort* __restrict__ Yout){
  __shared__ ushort At[64 * 256];
  const int t = threadIdx.x, w = t >> 6, l = t & 63;
  const long e0 = (long)blockIdx.x * 64;
  {
    int r = t >> 3, q = t & 7;
    #pragma unroll
    for (int c = 0; c < 2; c++){
      int col = 147 + c * 8 + q;
      if (col < 160){
        int byte = r * 384 + ((2 * col) ^ ((r & 7) << 4));
        *(ushort*)((char*)At + byte) = 0;
      }
    }
  }
  {
    const float4* src = (const float4*)(FB + e0 * 147);
    #pragma unroll
    for (int it = 0; it < 5; it++){
      int idx = t + it * 512;
      if (idx < 2352){
        float4 v = src[idx];
        int f0 = idx * 4;
        int row = (int)(((unsigned)f0 * 114131u) >> 24);  // f0 / 147
        int col = f0 - row * 147;
        #pragma unroll
        for (int j = 0; j < 4; j++){
          int byte = row * 384 + ((2 * col) ^ ((row & 7) << 4));
          *(ushort*)((char*)At + byte) = f2bf((&v.x)[j]);
          col++;
          if (col == 147){ col = 0; row++; }
        }
      }
    }
  }
  __syncthreads();
  const int lr = l & 15, lg = l >> 4;
  f32x4 acc[4][2] = {};
  for (int kb = 0; kb < 5; kb++){
    s16x8 a[4], b[2];
    #pragma unroll
    for (int m = 0; m < 4; m++){
      int row = m * 16 + lr;
      int cb = (kb * 64 + (lg << 4)) ^ ((row & 7) << 4);
      a[m] = *(const s16x8*)((const char*)At + row * 384 + cb);
    }
    #pragma unroll
    for (int n = 0; n < 2; n++)
      b[n] = *(const s16x8*)(Wif + (size_t)(((w * 2 + n) * 5 + kb) * 64 + l) * 8);
    #pragma unroll
    for (int m = 0; m < 4; m++)
      #pragma unroll
      for (int n = 0; n < 2; n++)
        acc[m][n] = mfma16(a[m], b[n], acc[m][n]);
  }
  __syncthreads();
  // epilogue 1: PRE-relu inp tile -> LDS (pitch 512)
  #pragma unroll
  for (int m = 0; m < 4; m++){
    #pragma unroll
    for (int n = 0; n < 2; n++){
      int col = w * 32 + n * 16 + lr;
      #pragma unroll
      for (int r = 0; r < 4; r++){
        int row = m * 16 + lg * 4 + r;
        int byte = row * 512 + ((2 * col) ^ ((row & 7) << 4));
        *(ushort*)((char*)At + byte) = f2bf(acc[m][n][r]);
      }
    }
  }
  __syncthreads();
  // wide pass 1: store inp rows (512B) scattered via pos; relu in place
  {
    const int chunk = t & 31, rg = t >> 5;
    #pragma unroll
    for (int it2 = 0; it2 < 4; it2++){
      int row = rg * 4 + it2;
      long pb = (long)pos[e0 + row] * 512;
      int lb = row * 512 + ((chunk * 16) ^ ((row & 7) << 4));
      uint4 v = *(uint4*)((char*)At + lb);
      *(uint4*)((char*)inp + pb + chunk * 16) = v;
      *(uint4*)((char*)At + lb) = relu8(v);
    }
  }
  __syncthreads();
  f32x4 acc2[4][2] = {};
  for (int kb = 0; kb < 8; kb++){
    s16x8 a[4], b[2];
    #pragma unroll
    for (int m = 0; m < 4; m++){
      int row = m * 16 + lr;
      int cb = (kb * 64 + (lg << 4)) ^ ((row & 7) << 4);
      a[m] = *(const s16x8*)((const char*)At + row * 512 + cb);
    }
    #pragma unroll
    for (int n = 0; n < 2; n++)
      b[n] = *(const s16x8*)(Whf + (size_t)(((w * 2 + n) * 8 + kb) * 64 + l) * 8);
    #pragma unroll
    for (int m = 0; m < 4; m++)
      #pragma unroll
      for (int n = 0; n < 2; n++)
        acc2[m][n] = mfma16(a[m], b[n], acc2[m][n]);
  }
  __syncthreads();
  #pragma unroll
  for (int m = 0; m < 4; m++){
    #pragma unroll
    for (int n = 0; n < 2; n++){
      int col = w * 32 + n * 16 + lr;
      #pragma unroll
      for (int r = 0; r < 4; r++){
        int row = m * 16 + lg * 4 + r;
        int byte = row * 512 + ((2 * col) ^ ((row & 7) << 4));
        *(ushort*)((char*)At + byte) = f2bf(acc2[m][n][r]);
      }
    }
  }
  __syncthreads();
  {
    const int chunk = t & 31, rg = t >> 5;
    #pragma unroll
    for (int it2 = 0; it2 < 4; it2++){
      int row = rg * 4 + it2;
      long pb = (long)pos[e0 + (row ^ 1)] * 512;
      int lb = row * 512 + ((chunk * 16) ^ ((row & 7) << 4));
      uint4 v = *(uint4*)((char*)At + lb);
      *(uint4*)((char*)Yout + pb + chunk * 16) = v;
    }
  }
}

// ---------------- dense E-row GEMM (512 thr), wide scatter ----------------
__global__ __launch_bounds__(512) void k_Y(
    const ushort* __restrict__ A, const ushort* __restrict__ Whf,
    const int* __restrict__ revp, ushort* __restrict__ Yout){
  __shared__ ushort At[64 * 256];
  const int t = threadIdx.x, w = t >> 6, l = t & 63;
  const long e0 = (long)blockIdx.x * 64;
  const char* Ab = (const char*)(A + e0 * 256);
  #pragma unroll
  for (int i = 0; i < 4; i++){
    int dbase = (i * 8 + w) * 1024;
    int d = dbase + l * 16;
    int sw = ((d >> 9) & 7) << 4;
    gload_lds16(Ab + (d ^ sw), (char*)At + dbase);
  }
  __syncthreads();
  const int lr = l & 15, lg = l >> 4;
  f32x4 acc[4][2] = {};
  for (int kb = 0; kb < 8; kb++){
    s16x8 a[4], b[2];
    #pragma unroll
    for (int m = 0; m < 4; m++){
      int row = m * 16 + lr;
      int cb = (kb * 64 + (lg << 4)) ^ ((row & 7) << 4);
      a[m] = *(const s16x8*)((const char*)At + row * 512 + cb);
    }
    #pragma unroll
    for (int n = 0; n < 2; n++){
      int fi = (w * 2 + n) * 8 + kb;
      b[n] = *(const s16x8*)(Whf + (size_t)(fi * 64 + l) * 8);
    }
    #pragma unroll
    for (int m = 0; m < 4; m++)
      #pragma unroll
      for (int n = 0; n < 2; n++)
        acc[m][n] = mfma16(a[m], b[n], acc[m][n]);
  }
  __syncthreads();
  #pragma unroll
  for (int m = 0; m < 4; m++){
    #pragma unroll
    for (int n = 0; n < 2; n++){
      int col = w * 32 + n * 16 + lr;
      #pragma unroll
      for (int r = 0; r < 4; r++){
        int row = m * 16 + lg * 4 + r;
        int byte = row * 512 + ((2 * col) ^ ((row & 7) << 4));
        *(ushort*)((char*)At + byte) = f2bf(acc[m][n][r]);
      }
    }
  }
  __syncthreads();
  {
    const int chunk = t & 31, rg = t >> 5;
    #pragma unroll
    for (int it2 = 0; it2 < 4; it2++){
      int row = rg * 4 + it2;
      long pb = (long)revp[e0 + row] * 512;
      int lb = row * 512 + ((chunk * 16) ^ ((row & 7) << 4));
      uint4 v = *(uint4*)((char*)At + lb);
      *(uint4*)((char*)Yout + pb + chunk * 16) = v;
    }
  }
}

// ---------------- fully-streaming combine: 2 atoms per 32-lane group ----------------
template<bool SCATTER>
__global__ __launch_bounds__(256) void k_comb(
    const ushort* __restrict__ Yd, const ushort* __restrict__ inp,
    const int* __restrict__ revp, const int* __restrict__ offs,
    ushort* __restrict__ M){
  const int t = threadIdx.x, g = t >> 5, h = t & 31;
  const int a0 = blockIdx.x * 16 + g * 2;
  const int beg = offs[a0], mid = offs[a0 + 1], end = offs[a0 + 2];
  const int n = end - beg, d0 = mid - beg;
  if (n == 0) return;
  if (n <= 8){
    s16x8 y[8], vi[8];
    int rv[8];
    #pragma unroll
    for (int k = 0; k < 8; k++) if (k < n){
      y[k]  = *(const s16x8*)(Yd  + (size_t)(beg + k) * 256 + h * 8);
      vi[k] = *(const s16x8*)(inp + (size_t)(beg + k) * 256 + h * 8);
      if (SCATTER) rv[k] = revp[beg + k];
    }
    float s0[8] = {}, s1[8] = {};
    #pragma unroll
    for (int k = 0; k < 8; k++) if (k < n){
      float m0 = (k < d0) ? 1.f : 0.f, m1 = 1.f - m0;
      #pragma unroll
      for (int j = 0; j < 8; j++){
        float vv = bf2f((ushort)y[k][j]);
        s0[j] += vv * m0;
        s1[j] += vv * m1;
      }
    }
    #pragma unroll
    for (int k = 0; k < 8; k++) if (k < n){
      bool f = (k < d0);
      float vv[8];
      #pragma unroll
      for (int j = 0; j < 8; j++){
        float s = f ? s0[j] : s1[j];
        float v = bf2f((ushort)vi[k][j]) + s - bf2f((ushort)y[k][j]);
        vv[j] = v > 0.f ? v : 0.f;
      }
      uint4 o;
      o.x = pk2(vv[0], vv[1]); o.y = pk2(vv[2], vv[3]);
      o.z = pk2(vv[4], vv[5]); o.w = pk2(vv[6], vv[7]);
      long wrow = SCATTER ? (long)rv[k] : (long)(beg + k);
      *(uint4*)(M + wrow * 256 + h * 8) = o;
    }
  } else {
    #pragma unroll
    for (int u = 0; u < 2; u++){
      int b = u ? mid : beg, e = u ? end : mid;
      float acc[8] = {};
      for (int i = b; i < e; i++){
        s16x8 yy = *(const s16x8*)(Yd + (size_t)i * 256 + h * 8);
        #pragma unroll
        for (int j = 0; j < 8; j++) acc[j] += bf2f((ushort)yy[j]);
      }
      for (int i = b; i < e; i++){
        s16x8 yy = *(const s16x8*)(Yd  + (size_t)i * 256 + h * 8);
        s16x8 ii = *(const s16x8*)(inp + (size_t)i * 256 + h * 8);
        float vv[8];
        #pragma unroll
        for (int j = 0; j < 8; j++){
          float v = bf2f((ushort)ii[j]) + acc[j] - bf2f((ushort)yy[j]);
          vv[j] = v > 0.f ? v : 0.f;
        }
        uint4 o;
        o.x = pk2(vv[0], vv[1]); o.y = pk2(vv[2], vv[3]);
        o.z = pk2(vv[4], vv[5]); o.w = pk2(vv[6], vv[7]);
        long wrow = SCATTER ? (long)revp[i] : (long)i;
        *(uint4*)(M + wrow * 256 + h * 8) = o;
      }
    }
  }
}

// ---------------- streaming per-atom row sum: 2 atoms per 32-lane group ----------------
__global__ __launch_bounds__(256) void k_amsg_seq(
    const ushort* __restrict__ Md, const int* __restrict__ offs,
    ushort* __restrict__ amsg){
  const int t = threadIdx.x, g = t >> 5, h = t & 31;
  const int a0 = blockIdx.x * 16 + g * 2;
  const int beg = offs[a0], mid = offs[a0 + 1], end = offs[a0 + 2];
  const int n = end - beg, d0 = mid - beg;
  float s0[8] = {}, s1[8] = {};
  if (n <= 8){
    s16x8 v[8];
    #pragma unroll
    for (int k = 0; k < 8; k++) if (k < n)
      v[k] = *(const s16x8*)(Md + (size_t)(beg + k) * 256 + h * 8);
    #pragma unroll
    for (int k = 0; k < 8; k++) if (k < n){
      float m0 = (k < d0) ? 1.f : 0.f, m1 = 1.f - m0;
      #pragma unroll
      for (int j = 0; j < 8; j++){
        float vv = bf2f((ushort)v[k][j]);
        s0[j] += vv * m0; s1[j] += vv * m1;
      }
    }
  } else {
    for (int i = beg; i < mid; i++){
      s16x8 v = *(const s16x8*)(Md + (size_t)i * 256 + h * 8);
      #pragma unroll
      for (int j = 0; j < 8; j++) s0[j] += bf2f((ushort)v[j]);
    }
    for (int i = mid; i < end; i++){
      s16x8 v = *(const s16x8*)(Md + (size_t)i * 256 + h * 8);
      #pragma unroll
      for (int j = 0; j < 8; j++) s1[j] += bf2f((ushort)v[j]);
    }
  }
  uint4 o0, o1;
  o0.x = pk2(s0[0], s0[1]); o0.y = pk2(s0[2], s0[3]);
  o0.z = pk2(s0[4], s0[5]); o0.w = pk2(s0[6], s0[7]);
  o1.x = pk2(s1[0], s1[1]); o1.y = pk2(s1[2], s1[3]);
  o1.z = pk2(s1[4], s1[5]); o1.w = pk2(s1[6], s1[7]);
  *(uint4*)(amsg + (size_t)a0 * 256 + h * 8) = o0;
  *(uint4*)(amsg + (size_t)(a0 + 1) * 256 + h * 8) = o1;
}

// ---------------- fused tail (512 thr): amsg gload_lds + ah GEMMs + node/proj ----------------
__global__ __launch_bounds__(512) void k_final2(
    const float* __restrict__ FA, const ushort* __restrict__ Wof1,
    const ushort* __restrict__ amsg, const ushort* __restrict__ Wof2,
    const float* __restrict__ b_o, const ushort* __restrict__ nWf,
    const ushort* __restrict__ eWf, const float* __restrict__ node_b,
    ushort* __restrict__ ah, float* __restrict__ out_node,
    float* __restrict__ proj){
  __shared__ ushort At[64 * 256];
  const int t = threadIdx.x, w = t >> 6, l = t & 63;
  const int lr = l & 15, lg = l >> 4;
  const long r0 = (long)blockIdx.x * 64;
  // ---- phase A: amsg tile via gload_lds (pitch 512, swizzled via pre-swizzled src) ----
  {
    const char* Mb = (const char*)(amsg + r0 * 256);
    #pragma unroll
    for (int i = 0; i < 4; i++){
      int dbase = (i * 8 + w) * 1024;
      int d = dbase + l * 16;
      int sw = ((d >> 9) & 7) << 4;
      gload_lds16(Mb + (d ^ sw), (char*)At + dbase);
    }
  }
  __syncthreads();
  f32x4 acc[4][2] = {};
  for (int kb = 0; kb < 8; kb++){
    s16x8 a[4], b[2];
    #pragma unroll
    for (int m = 0; m < 4; m++){
      int row = m * 16 + lr;
      int cb = (kb * 64 + (lg << 4)) ^ ((row & 7) << 4);
      a[m] = *(const s16x8*)((const char*)At + row * 512 + cb);
    }
    #pragma unroll
    for (int n = 0; n < 2; n++)
      b[n] = *(const s16x8*)(Wof2 + (size_t)(((w * 2 + n) * 8 + kb) * 64 + l) * 8);
    #pragma unroll
    for (int m = 0; m < 4; m++)
      #pragma unroll
      for (int n = 0; n < 2; n++)
        acc[m][n] = mfma16(a[m], b[n], acc[m][n]);
  }
  __syncthreads();
  // ---- phase B: stage fp32 f_atoms (pitch 384, swizzled) ----
  {
    int r = t >> 3, q = t & 7;
    #pragma unroll
    for (int c = 0; c < 4; c++){
      int col = 133 + c * 8 + q;
      if (col < 160){
        int byte = r * 384 + ((2 * col) ^ ((r & 7) << 4));
        *(ushort*)((char*)At + byte) = 0;
      }
    }
    const float4* src = (const float4*)(FA + r0 * 133);
    #pragma unroll
    for (int it = 0; it < 5; it++){
      int idx = t + it * 512;
      if (idx < 2128){
        float4 v = src[idx];
        int f0 = idx * 4;
        int row = (int)(((unsigned)f0 * 126146u) >> 24);  // f0 / 133
        int col = f0 - row * 133;
        #pragma unroll
        for (int j = 0; j < 4; j++){
          int byte = row * 384 + ((2 * col) ^ ((row & 7) << 4));
          *(ushort*)((char*)At + byte) = f2bf((&v.x)[j]);
          col++;
          if (col == 133){ col = 0; row++; }
        }
      }
    }
  }
  __syncthreads();
  for (int kb = 0; kb < 5; kb++){
    s16x8 a[4], b[2];
    #pragma unroll
    for (int m = 0; m < 4; m++){
      int row = m * 16 + lr;
      int cb = (kb * 64 + (lg << 4)) ^ ((row & 7) << 4);
      a[m] = *(const s16x8*)((const char*)At + row * 384 + cb);
    }
    #pragma unroll
    for (int n = 0; n < 2; n++)
      b[n] = *(const s16x8*)(Wof1 + (size_t)(((w * 2 + n) * 5 + kb) * 64 + l) * 8);
    #pragma unroll
    for (int m = 0; m < 4; m++)
      #pragma unroll
      for (int n = 0; n < 2; n++)
        acc[m][n] = mfma16(a[m], b[n], acc[m][n]);
  }
  __syncthreads();
  // ---- epilogue: ah tile -> LDS (pitch 512) ----
  #pragma unroll
  for (int m = 0; m < 4; m++){
    #pragma unroll
    for (int n = 0; n < 2; n++){
      int col = w * 32 + n * 16 + lr;
      float bo = b_o[col];
      #pragma unroll
      for (int r = 0; r < 4; r++){
        float v = acc[m][n][r] + bo;
        int row = m * 16 + lg * 4 + r;
        int byte = row * 512 + ((2 * col) ^ ((row & 7) << 4));
        *(ushort*)((char*)At + byte) = f2bf(v > 0.f ? v : 0.f);
      }
    }
  }
  __syncthreads();
  {
    const int chunk = t & 31, rg = t >> 5;
    #pragma unroll
    for (int it2 = 0; it2 < 4; it2++){
      int row = rg * 4 + it2;
      int lb = row * 512 + ((chunk * 16) ^ ((row & 7) << 4));
      uint4 v = *(uint4*)((char*)At + lb);
      *(uint4*)((char*)ah + (r0 + row) * 512 + chunk * 16) = v;
    }
  }
  // phase C: 10 output tiles over 8 waves: wave w does tiles {w, w+8} (skip >9)
  f32x4 acc3[4][2] = {};
  for (int kb = 0; kb < 8; kb++){
    s16x8 a[4];
    #pragma unroll
    for (int m = 0; m < 4; m++){
      int row = m * 16 + lr;
      int cb = (kb * 64 + (lg << 4)) ^ ((row & 7) << 4);
      a[m] = *(const s16x8*)((const char*)At + row * 512 + cb);
    }
    s16x8 b[2];
    #pragma unroll
    for (int j = 0; j < 2; j++){
      int nt = w + 8 * j;
      int ntc = (nt <= 9) ? nt : 0;
      if (ntc == 9)
        b[j] = *(const s16x8*)(eWf + (size_t)(kb * 64 + l) * 8);
      else
        b[j] = *(const s16x8*)(nWf + (size_t)((ntc * 8 + kb) * 64 + l) * 8);
    }
    #pragma unroll
    for (int m = 0; m < 4; m++)
      #pragma unroll
      for (int j = 0; j < 2; j++)
        acc3[m][j] = mfma16(a[m], b[j], acc3[m][j]);
  }
  #pragma unroll
  for (int j = 0; j < 2; j++){
    int nt = w + 8 * j;
    if (nt > 9) continue;
    if (nt == 9){
      #pragma unroll
      for (int m = 0; m < 4; m++)
        #pragma unroll
        for (int r = 0; r < 4; r++)
          proj[(r0 + m * 16 + lg * 4 + r) * 16 + lr] = acc3[m][j][r];
    } else {
      int col = nt * 16 + lr;
      if (col < AF){
        float nb = node_b[col];
        #pragma unroll
        for (int m = 0; m < 4; m++)
          #pragma unroll
          for (int r = 0; r < 4; r++)
            out_node[(r0 + m * 16 + lg * 4 + r) * AF + col] = acc3[m][j][r] + nb;
      }
    }
  }
}

__global__ void k_edge_out(const int* __restrict__ edge_index, const float* __restrict__ proj,
                           const float* __restrict__ edge_b, float* __restrict__ out_edge){
  int gid = blockIdx.x * 256 + threadIdx.x;
  int i = gid >> 4, c = gid & 15;
  if (c < BFdim){
    int s = edge_index[2 * i];
    int d = edge_index[NEDGES + 2 * i];
    out_edge[(size_t)i * BFdim + c] =
        0.5f * (proj[(size_t)s * 16 + c] + proj[(size_t)d * 16 + c]) + edge_b[c];
  }
}

// ---------------- molecule pooling ----------------
__global__ __launch_bounds__(256) void k_pool(const ushort* __restrict__ ah,
                                              const int* __restrict__ molst,
                                              float* __restrict__ gemb){
  const int t = threadIdx.x, w = t >> 6, l = t & 63;
  const int m = blockIdx.x * 4 + w;
  const int beg = molst[m], end = molst[m + 1];
  float a0 = 0, a1 = 0, a2 = 0, a3 = 0;
  for (int i = beg; i < end; i++){
    const ushort4 v = *(const ushort4*)(ah + (size_t)i * 256 + l * 4);
    a0 += bf2f(v.x); a1 += bf2f(v.y); a2 += bf2f(v.z); a3 += bf2f(v.w);
  }
  f32x4 o = {a0, a1, a2, a3};
  *(f32x4*)(gemb + (size_t)m * 256 + l * 4) = o;
}

// ---------------- graph head (fp32) ----------------
__global__ __launch_bounds__(256) void k_g1(const float* __restrict__ gemb,
                                            const float* __restrict__ gW1,
                                            const float* __restrict__ gb1,
                                            float* __restrict__ ghid){
  __shared__ float s[16 * 256];
  const int t = threadIdx.x;
  const int r0 = blockIdx.x * 16;
  for (int i = 0; i < 16; i++){
    int r = r0 + i;
    s[i * 256 + t] = (r < NMOLS) ? gemb[(size_t)r * 256 + t] : 0.f;
  }
  __syncthreads();
  float acc[16] = {};
  for (int k = 0; k < 256; k++){
    float wv = gW1[(size_t)k * 256 + t];
    #pragma unroll
    for (int i = 0; i < 16; i++) acc[i] += s[i * 256 + k] * wv;
  }
  float b = gb1[t];
  for (int i = 0; i < 16; i++){
    int r = r0 + i;
    if (r < NMOLS){ float v = acc[i] + b; ghid[(size_t)r * 256 + t] = v > 0.f ? v : 0.f; }
  }
}
__global__ void k_g2(const float* __restrict__ ghid, const float* __restrict__ gW2,
                     const float* __restrict__ gb2, float* __restrict__ outg){
  const int t = threadIdx.x, w = t >> 6, l = t & 63;
  const int m = blockIdx.x * 4 + w;
  f32x4 v = *(const f32x4*)(ghid + (size_t)m * 256 + l * 4);
  const f32x4 wv = *(const f32x4*)(gW2 + l * 4);
  float acc = v[0] * wv[0] + v[1] * wv[1] + v[2] * wv[2] + v[3] * wv[3];
  for (int ofs = 32; ofs; ofs >>= 1) acc += __shfl_down(acc, ofs, 64);
  if (l == 0) outg[m] = acc + gb2[0];
}

extern "C" void kernel_launch(void* const* d_in, const int* in_sizes, int n_in,
                              void* d_out, int out_size, void* d_ws, size_t ws_size,
                              hipStream_t stream){
  const float* f_atoms = (const float*)d_in[0];
  const float* f_bonds = (const float*)d_in[1];
  const float* W_i     = (const float*)d_in[2];
  const float* W_h     = (const float*)d_in[3];
  const float* W_o     = (const float*)d_in[4];
  const float* b_o     = (const float*)d_in[5];
  const float* node_W  = (const float*)d_in[6];
  const float* node_b  = (const float*)d_in[7];
  const float* edge_W  = (const float*)d_in[8];
  const float* edge_b  = (const float*)d_in[9];
  const float* g_W1    = (const float*)d_in[10];
  const float* g_b1    = (const float*)d_in[11];
  const float* g_W2    = (const float*)d_in[12];
  const float* g_b2    = (const float*)d_in[13];
  const int* edge_index = (const int*)d_in[14];
  const int* atom_mol   = (const int*)d_in[16];

  float* out_node  = (float*)d_out;
  float* out_edge  = out_node + (size_t)NATOMS * AF;
  float* out_graph = out_edge + (size_t)(NEDGES / 2) * BFdim;

  char* p = (char*)d_ws;
  auto alloc = [&](size_t b) -> char* { char* r = p; p += (b + 255) & ~(size_t)255; return r; };
  ushort* B1 = (ushort*)alloc((size_t)NEDGES * 256 * 2);  // inp (src-order)
  ushort* B2 = (ushort*)alloc((size_t)NEDGES * 256 * 2);  // M1 -> M2d
  ushort* B3 = (ushort*)alloc((size_t)NEDGES * 256 * 2);  // Y0d -> Y1d
  ushort* N1 = (ushort*)alloc((size_t)NATOMS * 256 * 2);  // ah
  ushort* N2 = (ushort*)alloc((size_t)NATOMS * 256 * 2);  // amsg
  float*  proj  = (float*)alloc((size_t)NATOMS * 16 * 4);
  float*  gemb  = (float*)alloc((size_t)NMOLS * 256 * 4);
  float*  ghid  = (float*)alloc((size_t)NMOLS * 256 * 4);
  ushort* Wif   = (ushort*)alloc(160 * 256 * 2);
  ushort* Wof1  = (ushort*)alloc(160 * 256 * 2);
  ushort* Whf   = (ushort*)alloc(256 * 256 * 2);
  ushort* Wof2  = (ushort*)alloc(256 * 256 * 2);
  ushort* nWf   = (ushort*)alloc(256 * 144 * 2);
  ushort* eWf   = (ushort*)alloc(256 * 16 * 2);
  int* deg    = (int*)alloc(NATOMS * 4);
  int* offs   = (int*)alloc((NATOMS + 1) * 4);
  int* cursor = (int*)alloc(NATOMS * 4);
  int* elist  = (int*)alloc(NEDGES * 4);
  int* pos    = (int*)alloc(NEDGES * 4);
  int* revp   = (int*)alloc(NEDGES * 4);
  int* bsum   = (int*)alloc(1568 * 4);
  int* boff   = (int*)alloc(1568 * 4);
  int* molst  = (int*)alloc((NMOLS + 1) * 4);
  if ((size_t)(p - (char*)d_ws) > ws_size) return;

  const int* srci = edge_index;  // CSR over SRC

  hipMemsetAsync(deg, 0, NATOMS * 4, stream);
  k_prep_weights<<<992, 256, 0, stream>>>(W_i, W_h, W_o, node_W, edge_W,
                                          Wif, Wof1, Whf, Wof2, nWf, eWf);
  // src-CSR + maps
  k_hist<<<3125, 256, 0, stream>>>(srci, deg);
  k_blocksum<<<NBLK, 256, 0, stream>>>(deg, bsum);
  k_scanblk<<<1, 1024, 0, stream>>>(bsum, boff);
  k_offs<<<NBLK, 256, 0, stream>>>(deg, boff, offs, cursor);
  k_fill<<<3125, 256, 0, stream>>>(srci, cursor, elist, pos);
  k_maps<<<3125, 256, 0, stream>>>(elist, pos, revp);
  k_molstart<<<51, 256, 0, stream>>>(atom_mol, molst);

  // stage fp32 f_bonds directly; inp[pos[e]] -> B1 ; Y0d[pos[e^1]] -> B3
  k_fused_inpY<<<12500, 512, 0, stream>>>(f_bonds, Wif, Whf, pos, B1, B3);
  // M1 = relu(inp + S0 - Y0d) -> B2 (all streams sequential)
  k_comb<false><<<25000, 256, 0, stream>>>(B3, B1, revp, offs, B2);
  // Y1d -> B3 (scatter via revp; Y0d dead)
  k_Y<<<12500, 512, 0, stream>>>(B2, Whf, revp, B3);
  // M2d = relu(inp + S1 - Y1d) scattered to dst-order -> B2 (M1 dead)
  k_comb<true><<<25000, 256, 0, stream>>>(B3, B1, revp, offs, B2);
  // amsg[a] = sum of contiguous M2d rows -> N2 (streaming)
  k_amsg_seq<<<25000, 256, 0, stream>>>(B2, offs, N2);
  // fused tail: amsg gload_lds + ah (global+LDS) + node/proj heads
  k_final2<<<6250, 512, 0, stream>>>(f_atoms, Wof1, N2, Wof2, b_o,
                                     nWf, eWf, node_b, N1, out_node, proj);
  // remaining heads
  k_pool<<<3250, 256, 0, stream>>>(N1, molst, gemb);
  k_edge_out<<<25000, 256, 0, stream>>>(edge_index, proj, edge_b, out_edge);
  k_g1<<<813, 256, 0, stream>>>(gemb, g_W1, g_b1, ghid);
  k_g2<<<3250, 256, 0, stream>>>(ghid, g_W2, g_b2, out_graph);
}

// Round 20
// 1656.038 us; speedup vs baseline: 1.0264x; 1.0264x over previous
//
#include <hip/hip_runtime.h>

#define NATOMS 400000
#define NEDGES 800000
#define NMOLS  13000
#define AF 133
#define BFdim 14
#define BFD 147

typedef __attribute__((ext_vector_type(8))) short  s16x8;
typedef __attribute__((ext_vector_type(8))) __bf16 b16x8;
typedef __attribute__((ext_vector_type(4))) float  f32x4;

__device__ __forceinline__ float bf2f(unsigned short u){
  union { unsigned int i; float f; } v; v.i = ((unsigned int)u) << 16; return v.f;
}
__device__ __forceinline__ unsigned short f2bf(float f){
  union { float ff; unsigned int i; } v; v.ff = f;
  unsigned int b = v.i + 0x7fffu + ((v.i >> 16) & 1u);
  return (unsigned short)(b >> 16);
}
__device__ __forceinline__ unsigned int pk2(float a, float b){
  unsigned int r;
  asm("v_cvt_pk_bf16_f32 %0, %1, %2" : "=v"(r) : "v"(a), "v"(b));
  return r;
}
__device__ __forceinline__ f32x4 mfma16(s16x8 a, s16x8 b, f32x4 c){
  return __builtin_amdgcn_mfma_f32_16x16x32_bf16(
      __builtin_bit_cast(b16x8, a), __builtin_bit_cast(b16x8, b), c, 0, 0, 0);
}
__device__ __forceinline__ void gload_lds16(const void* g, void* lds){
  __builtin_amdgcn_global_load_lds(
      (const __attribute__((address_space(1))) void*)g,
      (__attribute__((address_space(3))) void*)lds, 16, 0, 0);
}
__device__ __forceinline__ uint4 relu8(uint4 v){
  ushort* pv = (ushort*)&v;
  #pragma unroll
  for (int j = 0; j < 8; j++) pv[j] = (pv[j] & 0x8000u) ? 0 : pv[j];
  return v;
}

// ---------------- weight prep: fp32 -> bf16 fragment order ----------------
__global__ void k_prep_weights(const float* __restrict__ W_i, const float* __restrict__ W_h,
                               const float* __restrict__ W_o, const float* __restrict__ node_W,
                               const float* __restrict__ edge_W,
                               ushort* __restrict__ Wif, ushort* __restrict__ Wof1,
                               ushort* __restrict__ Whf, ushort* __restrict__ Wof2,
                               ushort* __restrict__ nWf, ushort* __restrict__ eWf){
  int gid = blockIdx.x * 256 + threadIdx.x;
  ushort* dst; const float* src; int KB, Kv, Ns, idx;
  if      (gid <  40960){ idx = gid;          dst = Wif;  src = W_i;          KB = 5; Kv = 147; Ns = 256; }
  else if (gid <  81920){ idx = gid -  40960; dst = Wof1; src = W_o;          KB = 5; Kv = 133; Ns = 256; }
  else if (gid < 147456){ idx = gid -  81920; dst = Whf;  src = W_h;          KB = 8; Kv = 256; Ns = 256; }
  else if (gid < 212992){ idx = gid - 147456; dst = Wof2; src = W_o + 133*256;KB = 8; Kv = 256; Ns = 256; }
  else if (gid < 249856){ idx = gid - 212992; dst = nWf;  src = node_W;       KB = 8; Kv = 256; Ns = 133; }
  else if (gid < 253952){ idx = gid - 249856; dst = eWf;  src = edge_W;       KB = 8; Kv = 256; Ns = 14;  }
  else return;
  int j = idx & 7, lane = (idx >> 3) & 63, fi = idx >> 9;
  int kb = fi % KB, nb = fi / KB;
  int k = kb * 32 + ((lane >> 4) << 3) + j;
  int n = nb * 16 + (lane & 15);
  float v = 0.f;
  if (k < Kv && n < Ns) v = src[(size_t)k * Ns + n];
  dst[idx] = f2bf(v);
}

// ---------------- CSR build over src ----------------
__global__ void k_hist(const int* __restrict__ key, int* __restrict__ deg){
  int e = blockIdx.x * 256 + threadIdx.x;
  if (e < NEDGES) atomicAdd(&deg[key[e]], 1);
}
__global__ void k_blocksum(const int* __restrict__ deg, int* __restrict__ bsum){
  __shared__ int s[256];
  int i = blockIdx.x * 256 + threadIdx.x;
  s[threadIdx.x] = (i < NATOMS) ? deg[i] : 0;
  __syncthreads();
  for (int st = 128; st > 0; st >>= 1){
    if (threadIdx.x < st) s[threadIdx.x] += s[threadIdx.x + st];
    __syncthreads();
  }
  if (threadIdx.x == 0) bsum[blockIdx.x] = s[0];
}
#define NBLK 1563
__global__ void k_scanblk(const int* __restrict__ bs, int* __restrict__ bo){
  __shared__ int s[2048];
  int t = threadIdx.x;
  s[2*t]   = (2*t   < NBLK) ? bs[2*t]   : 0;
  s[2*t+1] = (2*t+1 < NBLK) ? bs[2*t+1] : 0;
  int offset = 1;
  for (int d = 1024; d > 0; d >>= 1){
    __syncthreads();
    if (t < d){ int ai = offset*(2*t+1)-1, bi = offset*(2*t+2)-1; s[bi] += s[ai]; }
    offset <<= 1;
  }
  __syncthreads();
  if (t == 0) s[2047] = 0;
  for (int d = 1; d < 2048; d <<= 1){
    offset >>= 1;
    __syncthreads();
    if (t < d){ int ai = offset*(2*t+1)-1, bi = offset*(2*t+2)-1;
                int tmp = s[ai]; s[ai] = s[bi]; s[bi] += tmp; }
  }
  __syncthreads();
  if (2*t   < NBLK) bo[2*t]   = s[2*t];
  if (2*t+1 < NBLK) bo[2*t+1] = s[2*t+1];
}
__global__ void k_offs(const int* __restrict__ deg, const int* __restrict__ bo,
                       int* __restrict__ offs, int* __restrict__ cursor){
  __shared__ int s1[256], s2[256];
  int t = threadIdx.x;
  int i = blockIdx.x * 256 + t;
  int v = (i < NATOMS) ? deg[i] : 0;
  s1[t] = v;
  __syncthreads();
  int* rd = s1; int* wr = s2;
  for (int ofs = 1; ofs < 256; ofs <<= 1){
    wr[t] = rd[t] + ((t >= ofs) ? rd[t - ofs] : 0);
    __syncthreads();
    int* tmp = rd; rd = wr; wr = tmp;
  }
  if (i < NATOMS){
    int excl = rd[t] - v + bo[blockIdx.x];
    offs[i] = excl; cursor[i] = excl;
  }
  if (i == 0) offs[NATOMS] = NEDGES;
}
__global__ void k_fill(const int* __restrict__ key, int* __restrict__ cursor,
                       int* __restrict__ elist, int* __restrict__ pos){
  int e = blockIdx.x * 256 + threadIdx.x;
  if (e < NEDGES){ int p = atomicAdd(&cursor[key[e]], 1); elist[p] = e; pos[e] = p; }
}
__global__ void k_maps(const int* __restrict__ elist, const int* __restrict__ pos,
                       int* __restrict__ revp){
  int i = blockIdx.x * 256 + threadIdx.x;
  if (i < NEDGES) revp[i] = pos[elist[i] ^ 1];
}
__global__ void k_molstart(const int* __restrict__ atom_mol, int* __restrict__ molst){
  int m = blockIdx.x * 256 + threadIdx.x;
  if (m > NMOLS) return;
  int lo = 0, hi = NATOMS;
  while (lo < hi){ int mid = (lo + hi) >> 1; if (atom_mol[mid] < m) lo = mid + 1; else hi = mid; }
  molst[m] = lo;
}

// ---------------- fused (512 thr): stage fp32 f_bonds ; inp/Y0 GEMMs ; wide scatters ----------------
__global__ __launch_bounds__(512) void k_fused_inpY(
    const float* __restrict__ FB, const ushort* __restrict__ Wif,
    const ushort* __restrict__ Whf, const int* __restrict__ pos,
    ushort* __restrict__ inp, ushort* __restrict__ Yout){
  __shared__ ushort At[64 * 256];
  const int t = threadIdx.x, w = t >> 6, l = t & 63;
  const long e0 = (long)blockIdx.x * 64;
  {
    int r = t >> 3, q = t & 7;
    #pragma unroll
    for (int c = 0; c < 2; c++){
      int col = 147 + c * 8 + q;
      if (col < 160){
        int byte = r * 384 + ((2 * col) ^ ((r & 7) << 4));
        *(ushort*)((char*)At + byte) = 0;
      }
    }
  }
  {
    const float4* src = (const float4*)(FB + e0 * 147);
    #pragma unroll
    for (int it = 0; it < 5; it++){
      int idx = t + it * 512;
      if (idx < 2352){
        float4 v = src[idx];
        int f0 = idx * 4;
        int row = (int)(((unsigned)f0 * 114131u) >> 24);  // f0 / 147
        int col = f0 - row * 147;
        #pragma unroll
        for (int j = 0; j < 4; j++){
          int byte = row * 384 + ((2 * col) ^ ((row & 7) << 4));
          *(ushort*)((char*)At + byte) = f2bf((&v.x)[j]);
          col++;
          if (col == 147){ col = 0; row++; }
        }
      }
    }
  }
  __syncthreads();
  const int lr = l & 15, lg = l >> 4;
  f32x4 acc[4][2] = {};
  for (int kb = 0; kb < 5; kb++){
    s16x8 a[4], b[2];
    #pragma unroll
    for (int m = 0; m < 4; m++){
      int row = m * 16 + lr;
      int cb = (kb * 64 + (lg << 4)) ^ ((row & 7) << 4);
      a[m] = *(const s16x8*)((const char*)At + row * 384 + cb);
    }
    #pragma unroll
    for (int n = 0; n < 2; n++)
      b[n] = *(const s16x8*)(Wif + (size_t)(((w * 2 + n) * 5 + kb) * 64 + l) * 8);
    #pragma unroll
    for (int m = 0; m < 4; m++)
      #pragma unroll
      for (int n = 0; n < 2; n++)
        acc[m][n] = mfma16(a[m], b[n], acc[m][n]);
  }
  __syncthreads();
  // epilogue 1: PRE-relu inp tile -> LDS (pitch 512)
  #pragma unroll
  for (int m = 0; m < 4; m++){
    #pragma unroll
    for (int n = 0; n < 2; n++){
      int col = w * 32 + n * 16 + lr;
      #pragma unroll
      for (int r = 0; r < 4; r++){
        int row = m * 16 + lg * 4 + r;
        int byte = row * 512 + ((2 * col) ^ ((row & 7) << 4));
        *(ushort*)((char*)At + byte) = f2bf(acc[m][n][r]);
      }
    }
  }
  __syncthreads();
  // wide pass 1: store inp rows (512B) scattered via pos; relu in place
  {
    const int chunk = t & 31, rg = t >> 5;
    #pragma unroll
    for (int it2 = 0; it2 < 4; it2++){
      int row = rg * 4 + it2;
      long pb = (long)pos[e0 + row] * 512;
      int lb = row * 512 + ((chunk * 16) ^ ((row & 7) << 4));
      uint4 v = *(uint4*)((char*)At + lb);
      *(uint4*)((char*)inp + pb + chunk * 16) = v;
      *(uint4*)((char*)At + lb) = relu8(v);
    }
  }
  __syncthreads();
  f32x4 acc2[4][2] = {};
  for (int kb = 0; kb < 8; kb++){
    s16x8 a[4], b[2];
    #pragma unroll
    for (int m = 0; m < 4; m++){
      int row = m * 16 + lr;
      int cb = (kb * 64 + (lg << 4)) ^ ((row & 7) << 4);
      a[m] = *(const s16x8*)((const char*)At + row * 512 + cb);
    }
    #pragma unroll
    for (int n = 0; n < 2; n++)
      b[n] = *(const s16x8*)(Whf + (size_t)(((w * 2 + n) * 8 + kb) * 64 + l) * 8);
    #pragma unroll
    for (int m = 0; m < 4; m++)
      #pragma unroll
      for (int n = 0; n < 2; n++)
        acc2[m][n] = mfma16(a[m], b[n], acc2[m][n]);
  }
  __syncthreads();
  #pragma unroll
  for (int m = 0; m < 4; m++){
    #pragma unroll
    for (int n = 0; n < 2; n++){
      int col = w * 32 + n * 16 + lr;
      #pragma unroll
      for (int r = 0; r < 4; r++){
        int row = m * 16 + lg * 4 + r;
        int byte = row * 512 + ((2 * col) ^ ((row & 7) << 4));
        *(ushort*)((char*)At + byte) = f2bf(acc2[m][n][r]);
      }
    }
  }
  __syncthreads();
  {
    const int chunk = t & 31, rg = t >> 5;
    #pragma unroll
    for (int it2 = 0; it2 < 4; it2++){
      int row = rg * 4 + it2;
      long pb = (long)pos[e0 + (row ^ 1)] * 512;
      int lb = row * 512 + ((chunk * 16) ^ ((row & 7) << 4));
      uint4 v = *(uint4*)((char*)At + lb);
      *(uint4*)((char*)Yout + pb + chunk * 16) = v;
    }
  }
}

// ---------------- dense E-row GEMM (512 thr), wide scatter ----------------
__global__ __launch_bounds__(512) void k_Y(
    const ushort* __restrict__ A, const ushort* __restrict__ Whf,
    const int* __restrict__ revp, ushort* __restrict__ Yout){
  __shared__ ushort At[64 * 256];
  const int t = threadIdx.x, w = t >> 6, l = t & 63;
  const long e0 = (long)blockIdx.x * 64;
  const char* Ab = (const char*)(A + e0 * 256);
  #pragma unroll
  for (int i = 0; i < 4; i++){
    int dbase = (i * 8 + w) * 1024;
    int d = dbase + l * 16;
    int sw = ((d >> 9) & 7) << 4;
    gload_lds16(Ab + (d ^ sw), (char*)At + dbase);
  }
  __syncthreads();
  const int lr = l & 15, lg = l >> 4;
  f32x4 acc[4][2] = {};
  for (int kb = 0; kb < 8; kb++){
    s16x8 a[4], b[2];
    #pragma unroll
    for (int m = 0; m < 4; m++){
      int row = m * 16 + lr;
      int cb = (kb * 64 + (lg << 4)) ^ ((row & 7) << 4);
      a[m] = *(const s16x8*)((const char*)At + row * 512 + cb);
    }
    #pragma unroll
    for (int n = 0; n < 2; n++){
      int fi = (w * 2 + n) * 8 + kb;
      b[n] = *(const s16x8*)(Whf + (size_t)(fi * 64 + l) * 8);
    }
    #pragma unroll
    for (int m = 0; m < 4; m++)
      #pragma unroll
      for (int n = 0; n < 2; n++)
        acc[m][n] = mfma16(a[m], b[n], acc[m][n]);
  }
  __syncthreads();
  #pragma unroll
  for (int m = 0; m < 4; m++){
    #pragma unroll
    for (int n = 0; n < 2; n++){
      int col = w * 32 + n * 16 + lr;
      #pragma unroll
      for (int r = 0; r < 4; r++){
        int row = m * 16 + lg * 4 + r;
        int byte = row * 512 + ((2 * col) ^ ((row & 7) << 4));
        *(ushort*)((char*)At + byte) = f2bf(acc[m][n][r]);
      }
    }
  }
  __syncthreads();
  {
    const int chunk = t & 31, rg = t >> 5;
    #pragma unroll
    for (int it2 = 0; it2 < 4; it2++){
      int row = rg * 4 + it2;
      long pb = (long)revp[e0 + row] * 512;
      int lb = row * 512 + ((chunk * 16) ^ ((row & 7) << 4));
      uint4 v = *(uint4*)((char*)At + lb);
      *(uint4*)((char*)Yout + pb + chunk * 16) = v;
    }
  }
}

// ---------------- fully-streaming combine (round-18 proven form) ----------------
template<bool SCATTER>
__global__ __launch_bounds__(256) void k_comb(
    const ushort* __restrict__ Yd, const ushort* __restrict__ inp,
    const int* __restrict__ revp, const int* __restrict__ offs,
    ushort* __restrict__ M){
  const int t = threadIdx.x, g = t >> 5, h = t & 31;
  const int a = blockIdx.x * 8 + g;
  const int beg = offs[a], end = offs[a + 1];
  const int deg = end - beg;
  if (deg == 0) return;
  if (deg <= 4){
    s16x8 y[4], vi[4];
    #pragma unroll
    for (int k = 0; k < 4; k++) if (k < deg){
      y[k]  = *(const s16x8*)(Yd  + (size_t)(beg + k) * 256 + h * 8);
      vi[k] = *(const s16x8*)(inp + (size_t)(beg + k) * 256 + h * 8);
    }
    float acc[8] = {};
    #pragma unroll
    for (int k = 0; k < 4; k++) if (k < deg){
      #pragma unroll
      for (int j = 0; j < 8; j++) acc[j] += bf2f((ushort)y[k][j]);
    }
    #pragma unroll
    for (int k = 0; k < 4; k++) if (k < deg){
      float vv[8];
      #pragma unroll
      for (int j = 0; j < 8; j++){
        float v = bf2f((ushort)vi[k][j]) + acc[j] - bf2f((ushort)y[k][j]);
        vv[j] = v > 0.f ? v : 0.f;
      }
      uint4 o;
      o.x = pk2(vv[0], vv[1]); o.y = pk2(vv[2], vv[3]);
      o.z = pk2(vv[4], vv[5]); o.w = pk2(vv[6], vv[7]);
      long wrow = SCATTER ? (long)revp[beg + k] : (long)(beg + k);
      *(uint4*)(M + wrow * 256 + h * 8) = o;
    }
  } else {
    float acc[8] = {};
    for (int i = beg; i < end; i++){
      s16x8 y = *(const s16x8*)(Yd + (size_t)i * 256 + h * 8);
      #pragma unroll
      for (int j = 0; j < 8; j++) acc[j] += bf2f((ushort)y[j]);
    }
    for (int i = beg; i < end; i++){
      s16x8 y  = *(const s16x8*)(Yd  + (size_t)i * 256 + h * 8);
      s16x8 vi = *(const s16x8*)(inp + (size_t)i * 256 + h * 8);
      float vv[8];
      #pragma unroll
      for (int j = 0; j < 8; j++){
        float v = bf2f((ushort)vi[j]) + acc[j] - bf2f((ushort)y[j]);
        vv[j] = v > 0.f ? v : 0.f;
      }
      uint4 o;
      o.x = pk2(vv[0], vv[1]); o.y = pk2(vv[2], vv[3]);
      o.z = pk2(vv[4], vv[5]); o.w = pk2(vv[6], vv[7]);
      long wrow = SCATTER ? (long)revp[i] : (long)i;
      *(uint4*)(M + wrow * 256 + h * 8) = o;
    }
  }
}

// ---------------- streaming per-atom row sum (round-18 proven form) ----------------
__global__ __launch_bounds__(256) void k_amsg_seq(
    const ushort* __restrict__ Md, const int* __restrict__ offs,
    ushort* __restrict__ amsg){
  const int t = threadIdx.x, g = t >> 5, h = t & 31;
  const int a = blockIdx.x * 8 + g;
  const int beg = offs[a], end = offs[a + 1];
  float acc[8] = {};
  for (int i = beg; i < end; i++){
    s16x8 v = *(const s16x8*)(Md + (size_t)i * 256 + h * 8);
    #pragma unroll
    for (int j = 0; j < 8; j++) acc[j] += bf2f((ushort)v[j]);
  }
  uint4 ov;
  ov.x = pk2(acc[0], acc[1]); ov.y = pk2(acc[2], acc[3]);
  ov.z = pk2(acc[4], acc[5]); ov.w = pk2(acc[6], acc[7]);
  *(uint4*)(amsg + (size_t)a * 256 + h * 8) = ov;
}

// ---------------- fused tail (512 thr): amsg gload_lds + ah GEMMs + node/proj ----------------
__global__ __launch_bounds__(512) void k_final2(
    const float* __restrict__ FA, const ushort* __restrict__ Wof1,
    const ushort* __restrict__ amsg, const ushort* __restrict__ Wof2,
    const float* __restrict__ b_o, const ushort* __restrict__ nWf,
    const ushort* __restrict__ eWf, const float* __restrict__ node_b,
    ushort* __restrict__ ah, float* __restrict__ out_node,
    float* __restrict__ proj){
  __shared__ ushort At[64 * 256];
  const int t = threadIdx.x, w = t >> 6, l = t & 63;
  const int lr = l & 15, lg = l >> 4;
  const long r0 = (long)blockIdx.x * 64;
  // ---- phase A: amsg tile via gload_lds (pitch 512, swizzled via pre-swizzled src) ----
  {
    const char* Mb = (const char*)(amsg + r0 * 256);
    #pragma unroll
    for (int i = 0; i < 4; i++){
      int dbase = (i * 8 + w) * 1024;
      int d = dbase + l * 16;
      int sw = ((d >> 9) & 7) << 4;
      gload_lds16(Mb + (d ^ sw), (char*)At + dbase);
    }
  }
  __syncthreads();
  f32x4 acc[4][2] = {};
  for (int kb = 0; kb < 8; kb++){
    s16x8 a[4], b[2];
    #pragma unroll
    for (int m = 0; m < 4; m++){
      int row = m * 16 + lr;
      int cb = (kb * 64 + (lg << 4)) ^ ((row & 7) << 4);
      a[m] = *(const s16x8*)((const char*)At + row * 512 + cb);
    }
    #pragma unroll
    for (int n = 0; n < 2; n++)
      b[n] = *(const s16x8*)(Wof2 + (size_t)(((w * 2 + n) * 8 + kb) * 64 + l) * 8);
    #pragma unroll
    for (int m = 0; m < 4; m++)
      #pragma unroll
      for (int n = 0; n < 2; n++)
        acc[m][n] = mfma16(a[m], b[n], acc[m][n]);
  }
  __syncthreads();
  // ---- phase B: stage fp32 f_atoms (pitch 384, swizzled) ----
  {
    int r = t >> 3, q = t & 7;
    #pragma unroll
    for (int c = 0; c < 4; c++){
      int col = 133 + c * 8 + q;
      if (col < 160){
        int byte = r * 384 + ((2 * col) ^ ((r & 7) << 4));
        *(ushort*)((char*)At + byte) = 0;
      }
    }
    const float4* src = (const float4*)(FA + r0 * 133);
    #pragma unroll
    for (int it = 0; it < 5; it++){
      int idx = t + it * 512;
      if (idx < 2128){
        float4 v = src[idx];
        int f0 = idx * 4;
        int row = (int)(((unsigned)f0 * 126146u) >> 24);  // f0 / 133
        int col = f0 - row * 133;
        #pragma unroll
        for (int j = 0; j < 4; j++){
          int byte = row * 384 + ((2 * col) ^ ((row & 7) << 4));
          *(ushort*)((char*)At + byte) = f2bf((&v.x)[j]);
          col++;
          if (col == 133){ col = 0; row++; }
        }
      }
    }
  }
  __syncthreads();
  for (int kb = 0; kb < 5; kb++){
    s16x8 a[4], b[2];
    #pragma unroll
    for (int m = 0; m < 4; m++){
      int row = m * 16 + lr;
      int cb = (kb * 64 + (lg << 4)) ^ ((row & 7) << 4);
      a[m] = *(const s16x8*)((const char*)At + row * 384 + cb);
    }
    #pragma unroll
    for (int n = 0; n < 2; n++)
      b[n] = *(const s16x8*)(Wof1 + (size_t)(((w * 2 + n) * 5 + kb) * 64 + l) * 8);
    #pragma unroll
    for (int m = 0; m < 4; m++)
      #pragma unroll
      for (int n = 0; n < 2; n++)
        acc[m][n] = mfma16(a[m], b[n], acc[m][n]);
  }
  __syncthreads();
  // ---- epilogue: ah tile -> LDS (pitch 512) ----
  #pragma unroll
  for (int m = 0; m < 4; m++){
    #pragma unroll
    for (int n = 0; n < 2; n++){
      int col = w * 32 + n * 16 + lr;
      float bo = b_o[col];
      #pragma unroll
      for (int r = 0; r < 4; r++){
        float v = acc[m][n][r] + bo;
        int row = m * 16 + lg * 4 + r;
        int byte = row * 512 + ((2 * col) ^ ((row & 7) << 4));
        *(ushort*)((char*)At + byte) = f2bf(v > 0.f ? v : 0.f);
      }
    }
  }
  __syncthreads();
  {
    const int chunk = t & 31, rg = t >> 5;
    #pragma unroll
    for (int it2 = 0; it2 < 4; it2++){
      int row = rg * 4 + it2;
      int lb = row * 512 + ((chunk * 16) ^ ((row & 7) << 4));
      uint4 v = *(uint4*)((char*)At + lb);
      *(uint4*)((char*)ah + (r0 + row) * 512 + chunk * 16) = v;
    }
  }
  // phase C: 10 output tiles over 8 waves: wave w does tiles {w, w+8} (skip >9)
  f32x4 acc3[4][2] = {};
  for (int kb = 0; kb < 8; kb++){
    s16x8 a[4];
    #pragma unroll
    for (int m = 0; m < 4; m++){
      int row = m * 16 + lr;
      int cb = (kb * 64 + (lg << 4)) ^ ((row & 7) << 4);
      a[m] = *(const s16x8*)((const char*)At + row * 512 + cb);
    }
    s16x8 b[2];
    #pragma unroll
    for (int j = 0; j < 2; j++){
      int nt = w + 8 * j;
      int ntc = (nt <= 9) ? nt : 0;
      if (ntc == 9)
        b[j] = *(const s16x8*)(eWf + (size_t)(kb * 64 + l) * 8);
      else
        b[j] = *(const s16x8*)(nWf + (size_t)((ntc * 8 + kb) * 64 + l) * 8);
    }
    #pragma unroll
    for (int m = 0; m < 4; m++)
      #pragma unroll
      for (int j = 0; j < 2; j++)
        acc3[m][j] = mfma16(a[m], b[j], acc3[m][j]);
  }
  #pragma unroll
  for (int j = 0; j < 2; j++){
    int nt = w + 8 * j;
    if (nt > 9) continue;
    if (nt == 9){
      #pragma unroll
      for (int m = 0; m < 4; m++)
        #pragma unroll
        for (int r = 0; r < 4; r++)
          proj[(r0 + m * 16 + lg * 4 + r) * 16 + lr] = acc3[m][j][r];
    } else {
      int col = nt * 16 + lr;
      if (col < AF){
        float nb = node_b[col];
        #pragma unroll
        for (int m = 0; m < 4; m++)
          #pragma unroll
          for (int r = 0; r < 4; r++)
            out_node[(r0 + m * 16 + lg * 4 + r) * AF + col] = acc3[m][j][r] + nb;
      }
    }
  }
}

__global__ void k_edge_out(const int* __restrict__ edge_index, const float* __restrict__ proj,
                           const float* __restrict__ edge_b, float* __restrict__ out_edge){
  int gid = blockIdx.x * 256 + threadIdx.x;
  int i = gid >> 4, c = gid & 15;
  if (c < BFdim){
    int s = edge_index[2 * i];
    int d = edge_index[NEDGES + 2 * i];
    out_edge[(size_t)i * BFdim + c] =
        0.5f * (proj[(size_t)s * 16 + c] + proj[(size_t)d * 16 + c]) + edge_b[c];
  }
}

// ---------------- molecule pooling ----------------
__global__ __launch_bounds__(256) void k_pool(const ushort* __restrict__ ah,
                                              const int* __restrict__ molst,
                                              float* __restrict__ gemb){
  const int t = threadIdx.x, w = t >> 6, l = t & 63;
  const int m = blockIdx.x * 4 + w;
  const int beg = molst[m], end = molst[m + 1];
  float a0 = 0, a1 = 0, a2 = 0, a3 = 0;
  for (int i = beg; i < end; i++){
    const ushort4 v = *(const ushort4*)(ah + (size_t)i * 256 + l * 4);
    a0 += bf2f(v.x); a1 += bf2f(v.y); a2 += bf2f(v.z); a3 += bf2f(v.w);
  }
  f32x4 o = {a0, a1, a2, a3};
  *(f32x4*)(gemb + (size_t)m * 256 + l * 4) = o;
}

// ---------------- graph head (fp32) ----------------
__global__ __launch_bounds__(256) void k_g1(const float* __restrict__ gemb,
                                            const float* __restrict__ gW1,
                                            const float* __restrict__ gb1,
                                            float* __restrict__ ghid){
  __shared__ float s[16 * 256];
  const int t = threadIdx.x;
  const int r0 = blockIdx.x * 16;
  for (int i = 0; i < 16; i++){
    int r = r0 + i;
    s[i * 256 + t] = (r < NMOLS) ? gemb[(size_t)r * 256 + t] : 0.f;
  }
  __syncthreads();
  float acc[16] = {};
  for (int k = 0; k < 256; k++){
    float wv = gW1[(size_t)k * 256 + t];
    #pragma unroll
    for (int i = 0; i < 16; i++) acc[i] += s[i * 256 + k] * wv;
  }
  float b = gb1[t];
  for (int i = 0; i < 16; i++){
    int r = r0 + i;
    if (r < NMOLS){ float v = acc[i] + b; ghid[(size_t)r * 256 + t] = v > 0.f ? v : 0.f; }
  }
}
__global__ void k_g2(const float* __restrict__ ghid, const float* __restrict__ gW2,
                     const float* __restrict__ gb2, float* __restrict__ outg){
  const int t = threadIdx.x, w = t >> 6, l = t & 63;
  const int m = blockIdx.x * 4 + w;
  f32x4 v = *(const f32x4*)(ghid + (size_t)m * 256 + l * 4);
  const f32x4 wv = *(const f32x4*)(gW2 + l * 4);
  float acc = v[0] * wv[0] + v[1] * wv[1] + v[2] * wv[2] + v[3] * wv[3];
  for (int ofs = 32; ofs; ofs >>= 1) acc += __shfl_down(acc, ofs, 64);
  if (l == 0) outg[m] = acc + gb2[0];
}

extern "C" void kernel_launch(void* const* d_in, const int* in_sizes, int n_in,
                              void* d_out, int out_size, void* d_ws, size_t ws_size,
                              hipStream_t stream){
  const float* f_atoms = (const float*)d_in[0];
  const float* f_bonds = (const float*)d_in[1];
  const float* W_i     = (const float*)d_in[2];
  const float* W_h     = (const float*)d_in[3];
  const float* W_o     = (const float*)d_in[4];
  const float* b_o     = (const float*)d_in[5];
  const float* node_W  = (const float*)d_in[6];
  const float* node_b  = (const float*)d_in[7];
  const float* edge_W  = (const float*)d_in[8];
  const float* edge_b  = (const float*)d_in[9];
  const float* g_W1    = (const float*)d_in[10];
  const float* g_b1    = (const float*)d_in[11];
  const float* g_W2    = (const float*)d_in[12];
  const float* g_b2    = (const float*)d_in[13];
  const int* edge_index = (const int*)d_in[14];
  const int* atom_mol   = (const int*)d_in[16];

  float* out_node  = (float*)d_out;
  float* out_edge  = out_node + (size_t)NATOMS * AF;
  float* out_graph = out_edge + (size_t)(NEDGES / 2) * BFdim;

  char* p = (char*)d_ws;
  auto alloc = [&](size_t b) -> char* { char* r = p; p += (b + 255) & ~(size_t)255; return r; };
  ushort* B1 = (ushort*)alloc((size_t)NEDGES * 256 * 2);  // inp (src-order)
  ushort* B2 = (ushort*)alloc((size_t)NEDGES * 256 * 2);  // M1 -> M2d
  ushort* B3 = (ushort*)alloc((size_t)NEDGES * 256 * 2);  // Y0d -> Y1d
  ushort* N1 = (ushort*)alloc((size_t)NATOMS * 256 * 2);  // ah
  ushort* N2 = (ushort*)alloc((size_t)NATOMS * 256 * 2);  // amsg
  float*  proj  = (float*)alloc((size_t)NATOMS * 16 * 4);
  float*  gemb  = (float*)alloc((size_t)NMOLS * 256 * 4);
  float*  ghid  = (float*)alloc((size_t)NMOLS * 256 * 4);
  ushort* Wif   = (ushort*)alloc(160 * 256 * 2);
  ushort* Wof1  = (ushort*)alloc(160 * 256 * 2);
  ushort* Whf   = (ushort*)alloc(256 * 256 * 2);
  ushort* Wof2  = (ushort*)alloc(256 * 256 * 2);
  ushort* nWf   = (ushort*)alloc(256 * 144 * 2);
  ushort* eWf   = (ushort*)alloc(256 * 16 * 2);
  int* deg    = (int*)alloc(NATOMS * 4);
  int* offs   = (int*)alloc((NATOMS + 1) * 4);
  int* cursor = (int*)alloc(NATOMS * 4);
  int* elist  = (int*)alloc(NEDGES * 4);
  int* pos    = (int*)alloc(NEDGES * 4);
  int* revp   = (int*)alloc(NEDGES * 4);
  int* bsum   = (int*)alloc(1568 * 4);
  int* boff   = (int*)alloc(1568 * 4);
  int* molst  = (int*)alloc((NMOLS + 1) * 4);
  if ((size_t)(p - (char*)d_ws) > ws_size) return;

  const int* srci = edge_index;  // CSR over SRC

  hipMemsetAsync(deg, 0, NATOMS * 4, stream);
  k_prep_weights<<<992, 256, 0, stream>>>(W_i, W_h, W_o, node_W, edge_W,
                                          Wif, Wof1, Whf, Wof2, nWf, eWf);
  // src-CSR + maps
  k_hist<<<3125, 256, 0, stream>>>(srci, deg);
  k_blocksum<<<NBLK, 256, 0, stream>>>(deg, bsum);
  k_scanblk<<<1, 1024, 0, stream>>>(bsum, boff);
  k_offs<<<NBLK, 256, 0, stream>>>(deg, boff, offs, cursor);
  k_fill<<<3125, 256, 0, stream>>>(srci, cursor, elist, pos);
  k_maps<<<3125, 256, 0, stream>>>(elist, pos, revp);
  k_molstart<<<51, 256, 0, stream>>>(atom_mol, molst);

  // stage fp32 f_bonds directly; inp[pos[e]] -> B1 ; Y0d[pos[e^1]] -> B3
  k_fused_inpY<<<12500, 512, 0, stream>>>(f_bonds, Wif, Whf, pos, B1, B3);
  // M1 = relu(inp + S0 - Y0d) -> B2 (all streams sequential)
  k_comb<false><<<50000, 256, 0, stream>>>(B3, B1, revp, offs, B2);
  // Y1d -> B3 (scatter via revp; Y0d dead)
  k_Y<<<12500, 512, 0, stream>>>(B2, Whf, revp, B3);
  // M2d = relu(inp + S1 - Y1d) scattered to dst-order -> B2 (M1 dead)
  k_comb<true><<<50000, 256, 0, stream>>>(B3, B1, revp, offs, B2);
  // amsg[a] = sum of contiguous M2d rows -> N2 (streaming)
  k_amsg_seq<<<50000, 256, 0, stream>>>(B2, offs, N2);
  // fused tail: amsg gload_lds + ah (global+LDS) + node/proj heads
  k_final2<<<6250, 512, 0, stream>>>(f_atoms, Wof1, N2, Wof2, b_o,
                                     nWf, eWf, node_b, N1, out_node, proj);
  // remaining heads
  k_pool<<<3250, 256, 0, stream>>>(N1, molst, gemb);
  k_edge_out<<<25000, 256, 0, stream>>>(edge_index, proj, edge_b, out_edge);
  k_g1<<<813, 256, 0, stream>>>(gemb, g_W1, g_b1, ghid);
  k_g2<<<3250, 256, 0, stream>>>(ghid, g_W2, g_b2, out_graph);
}